// Round 14
// baseline (499.821 us; speedup 1.0000x reference)
//
#include <hip/hip_runtime.h>

#define N_NODES 50000
#define E_EDGES 262144

typedef __attribute__((ext_vector_type(8))) _Float16 f16x8;
typedef __attribute__((ext_vector_type(2))) _Float16 f16x2;
typedef __attribute__((ext_vector_type(16))) float f32x16;

union V16 { uint4 u; f16x8 h; };
union U32 { unsigned u; f16x2 p; };

// pack two f32 -> two f16 (RNE), a in low half
__device__ __forceinline__ unsigned h2pack(float a, float b) {
  union { _Float16 h[2]; unsigned u; } r;
  r.h[0] = (_Float16)a;
  r.h[1] = (_Float16)b;
  return r.u;
}
__device__ __forceinline__ void async_gather16(const void* gptr, void* lptr) {
  __builtin_amdgcn_global_load_lds(
      (const __attribute__((address_space(1))) void*)gptr,
      (__attribute__((address_space(3))) void*)lptr, 16, 0, 0);
}

// ---- fused prep (unchanged): blocks [0,6250) cvt node fp32->fp16;
//      [6250,6506) repack W1 into 16-B units [step(8)][sq(16)][col(512)],
//      unit = W1[k0..k0+8)[col], k0 = s*256 + step*32 + qd*8. ----
__global__ __launch_bounds__(256) void prep_all_kernel(
    const float* __restrict__ node, const float* __restrict__ w1,
    unsigned short* __restrict__ nodeb, unsigned short* __restrict__ w1pp2) {
  const int bx = blockIdx.x;
  if (bx < 6250) {
    int i = (bx * 256 + threadIdx.x) * 8;
    float4 f0 = *(const float4*)(node + i);
    float4 f1 = *(const float4*)(node + i + 4);
    uint4 o;
    o.x = h2pack(f0.x, f0.y);
    o.y = h2pack(f0.z, f0.w);
    o.z = h2pack(f1.x, f1.y);
    o.w = h2pack(f1.z, f1.w);
    *(uint4*)(nodeb + i) = o;
  } else {
    int t = (bx - 6250) * 256 + threadIdx.x;  // 65536 units
    int step = t >> 13;
    int rem = t & 8191;
    int sq = rem >> 9;
    int col = rem & 511;
    int s = sq >> 2, qd = sq & 3;
    int k0 = s * 256 + step * 32 + qd * 8;
    float f[8];
#pragma unroll
    for (int i = 0; i < 8; ++i) f[i] = w1[(size_t)(k0 + i) * 512 + col];
    uint4 o;
    o.x = h2pack(f[0], f[1]);
    o.y = h2pack(f[2], f[3]);
    o.z = h2pack(f[4], f[5]);
    o.w = h2pack(f[6], f[7]);
    *(uint4*)(w1pp2 + (size_t)t * 8) = o;
  }
}

// ---- main fused kernel R14: byte-identical to the VERIFIED R12 body (512 thr,
//      8 waves, 64e x 512c, wave 64e x 64c, 32x32x16 f16 MFMA, conflict-free
//      u^(row&31) swizzle, VGPR 64 + acc 64 = 128 total -> 4 waves/SIMD, Occ 44%,
//      edge 316 us) EXCEPT one isolated change: COARSE s_setprio (2 ops/step)
//      wrapping only the s=0/s=1 pure-MFMA block (operands already in regs ->
//      no live-range extension). R13's fine-grained setprio + epilogue rewrite
//      grew VGPR 64->88 and fell off the 128-total occupancy cliff (-17%).
//      HARD GATE: VGPR must stay 64. If not, revert to R12 verbatim. ----
__global__ __launch_bounds__(512) void edge_mlp_kernel(
    const unsigned short* __restrict__ nodeb,  // [50000][256] fp16
    const unsigned short* __restrict__ w1pp2,  // repacked W1 (see prep)
    const int* __restrict__ src,
    const int* __restrict__ dst,
    const float* __restrict__ b1,
    const float* __restrict__ w2,   // [512][2] fp32
    const float* __restrict__ b2,   // [2] fp32
    float* __restrict__ out) {      // [E][2] fp32 (written once, no pre-init)
  // hi: [0,32K) — 64 edges x 512 B; hj: [32K,64K)
  // 16-B unit slot for (edge row, unit u): row*32 + (u ^ (row&31))
  __shared__ char smem[65536];

  const int tid = threadIdx.x;
  const int wid = tid >> 6;      // 0..7 -> 8 waves x 64 cols = all 512 cols
  const int lane = tid & 63;
  const int l32 = lane & 31;
  const int khalf = lane >> 5;   // k-half within a K16 slice
  const int bx = blockIdx.x;     // 0..4095
  // XCD swizzle: xc = bx&7; neighbor m-tiles share an XCD
  const int xc = bx & 7;
  const int m_idx = (bx >> 3) * 8 + xc;      // 0..4095 (64-edge tiles)
  const int row0 = m_idx * 64;
  const int n0 = wid * 64;

  const char* nodeB = (const char*)nodeb;
  const char* w1B = (const char*)w1pp2;

  // ---- B load: addr = w1s + bQ + s*32768 + slice*16384 + nt2*512 (+step*131072) ----
  const unsigned bQ = (unsigned)(khalf * 8192 + (n0 + l32) * 16);
  const char* w1s = w1B;

  // ---- A reader: row = mt2*32 + l32; unit u = step*4+slice*2+khalf
  //      byte = row*512 + ((u ^ l32) << 4) ----
  const unsigned aXor = (unsigned)l32;
  const unsigned aBase = (unsigned)(l32 * 512);

  f32x16 acc[2][2];
#pragma unroll
  for (int mt2 = 0; mt2 < 2; ++mt2)
#pragma unroll
    for (int nt2 = 0; nt2 < 2; ++nt2)
#pragma unroll
      for (int r = 0; r < 16; ++r)
        acc[mt2][nt2][r] = 0.f;

  // ---- prologue: stage ALL of A (hi+hj, 64 edges x 512 B each region) ----
  // call c stages slots v = c*512+tid; e = c*16 + (tid>>5); w = tid&31.
  // LDS dest linear; source carries XOR u_src = w ^ (e&31), e&31 = ((c&1)<<4)|(tid>>5).
  {
    const int eh = tid >> 5;                                        // 0..15
#pragma unroll
    for (int c = 0; c < 4; ++c) {
      int e = c * 16 + eh;
      unsigned xv = (unsigned)((((c & 1) << 4) | eh));
      unsigned wsw = (((unsigned)(tid & 31)) ^ xv) << 4;
      unsigned so = ((unsigned)src[row0 + e] << 9) + wsw;
      unsigned do_ = ((unsigned)dst[row0 + e] << 9) + wsw;
      async_gather16(nodeB + so, smem + c * 8192 + wid * 1024);
      async_gather16(nodeB + do_, smem + 32768 + c * 8192 + wid * 1024);
    }
  }
  __syncthreads();  // staging barrier

#pragma unroll 2
  for (int step = 0; step < 8; ++step) {
    // B(t) loads — compiler emits fine-grained vmcnt
    V16 bf[4][2][2];  // [s][slice][nt2]
#pragma unroll
    for (int s = 0; s < 4; ++s)
#pragma unroll
      for (int sl = 0; sl < 2; ++sl)
#pragma unroll
        for (int nt2 = 0; nt2 < 2; ++nt2)
          bf[s][sl][nt2].u = *(const uint4*)(
              w1s + (bQ + (unsigned)(s * 32768 + sl * 16384 + nt2 * 512)));
    // A fragments from LDS (read-only, no sync needed)
    V16 hi[2][2], hj[2][2];  // [mt2][slice]
#pragma unroll
    for (int mt2 = 0; mt2 < 2; ++mt2)
#pragma unroll
      for (int sl = 0; sl < 2; ++sl) {
        unsigned u = (unsigned)(step * 4 + sl * 2 + khalf);
        unsigned ao = (unsigned)(mt2 * 16384) + aBase + ((u ^ aXor) << 4);
        hi[mt2][sl].u = *(const uint4*)(smem + ao);
        hj[mt2][sl].u = *(const uint4*)(smem + 32768 + ao);
      }
    // MFMA s=0 (hi), s=1 (hj) — pure-MFMA region, coarse prio boost (T5)
    __builtin_amdgcn_s_setprio(1);
#pragma unroll
    for (int mt2 = 0; mt2 < 2; ++mt2)
#pragma unroll
      for (int sl = 0; sl < 2; ++sl)
#pragma unroll
        for (int nt2 = 0; nt2 < 2; ++nt2)
          acc[mt2][nt2] = __builtin_amdgcn_mfma_f32_32x32x16_f16(
              hi[mt2][sl].h, bf[0][sl][nt2].h, acc[mt2][nt2], 0, 0, 0);
#pragma unroll
    for (int mt2 = 0; mt2 < 2; ++mt2)
#pragma unroll
      for (int sl = 0; sl < 2; ++sl)
#pragma unroll
        for (int nt2 = 0; nt2 < 2; ++nt2)
          acc[mt2][nt2] = __builtin_amdgcn_mfma_f32_32x32x16_f16(
              hj[mt2][sl].h, bf[1][sl][nt2].h, acc[mt2][nt2], 0, 0, 0);
    __builtin_amdgcn_s_setprio(0);
    // build a2=|hi-hj|, a3=hi*hj with packed fp16 (3 VALU/word), MFMA s=2,3
#pragma unroll
    for (int mt2 = 0; mt2 < 2; ++mt2)
#pragma unroll
      for (int sl = 0; sl < 2; ++sl) {
        const unsigned hw[4] = {hi[mt2][sl].u.x, hi[mt2][sl].u.y, hi[mt2][sl].u.z, hi[mt2][sl].u.w};
        const unsigned jw[4] = {hj[mt2][sl].u.x, hj[mt2][sl].u.y, hj[mt2][sl].u.z, hj[mt2][sl].u.w};
        unsigned d[4], pr[4];
#pragma unroll
        for (int w = 0; w < 4; ++w) {
          U32 hx, jx, dd, pp;
          hx.u = hw[w];
          jx.u = jw[w];
          dd.p = hx.p - jx.p;            // v_pk_add_f16 (neg mod)
          d[w] = dd.u & 0x7fff7fffu;     // abs: clear sign bits (exact)
          pp.p = hx.p * jx.p;            // v_pk_mul_f16
          pr[w] = pp.u;
        }
        V16 a2, a3;
        a2.u = make_uint4(d[0], d[1], d[2], d[3]);
        a3.u = make_uint4(pr[0], pr[1], pr[2], pr[3]);
#pragma unroll
        for (int nt2 = 0; nt2 < 2; ++nt2)
          acc[mt2][nt2] = __builtin_amdgcn_mfma_f32_32x32x16_f16(
              a2.h, bf[2][sl][nt2].h, acc[mt2][nt2], 0, 0, 0);
#pragma unroll
        for (int nt2 = 0; nt2 < 2; ++nt2)
          acc[mt2][nt2] = __builtin_amdgcn_mfma_f32_32x32x16_f16(
              a3.h, bf[3][sl][nt2].h, acc[mt2][nt2], 0, 0, 0);
      }
    w1s += 131072;
  }

  // ---- epilogue (R12-exact): bias + ReLU + W2, 32-lane-half shuffle reduce,
  //      LDS cross-wave reduction (smem reused) + ONE plain store per element ----
  float* red = (float*)smem;   // [8 waves][64 edges][2] f32 = 4 KB
  __syncthreads();             // all waves done reading A tiles from LDS
  float b1v[2], w20[2], w21[2];
#pragma unroll
  for (int nt2 = 0; nt2 < 2; ++nt2) {
    int gc = n0 + nt2 * 32 + l32;
    b1v[nt2] = b1[gc];
    w20[nt2] = w2[gc * 2 + 0];
    w21[nt2] = w2[gc * 2 + 1];
  }
#pragma unroll
  for (int mt2 = 0; mt2 < 2; ++mt2) {
#pragma unroll
    for (int r = 0; r < 16; ++r) {
      float pc0 = 0.f, pc1 = 0.f;
#pragma unroll
      for (int nt2 = 0; nt2 < 2; ++nt2) {
        float v = fmaxf(acc[mt2][nt2][r] + b1v[nt2], 0.f);
        pc0 = fmaf(v, w20[nt2], pc0);
        pc1 = fmaf(v, w21[nt2], pc1);
      }
      // reduce over the 32-lane half (cols); halves hold different rows
#pragma unroll
      for (int off = 1; off < 32; off <<= 1) {
        pc0 += __shfl_xor(pc0, off);
        pc1 += __shfl_xor(pc1, off);
      }
      // C/D: row = (r&3) + 8*(r>>2) + 4*khalf
      int el = mt2 * 32 + (r & 3) + 8 * (r >> 2) + 4 * khalf;
      if (l32 == 0) red[wid * 128 + el * 2 + 0] = pc0;
      if (l32 == 1) red[wid * 128 + el * 2 + 1] = pc1;
    }
  }
  __syncthreads();
  if (tid < 128) {
    // tid = el*2 + c
    float s = b2[tid & 1];
#pragma unroll
    for (int w = 0; w < 8; ++w) s += red[w * 128 + tid];
    out[(size_t)row0 * 2 + tid] = s;
  }
}

extern "C" void kernel_launch(void* const* d_in, const int* in_sizes, int n_in,
                              void* d_out, int out_size, void* d_ws, size_t ws_size,
                              hipStream_t stream) {
  const float* node = (const float*)d_in[0];
  const int* src = (const int*)d_in[1];
  const int* dst = (const int*)d_in[2];
  const float* W1 = (const float*)d_in[3];
  const float* b1 = (const float*)d_in[4];
  const float* W2 = (const float*)d_in[5];
  const float* b2 = (const float*)d_in[6];
  float* out = (float*)d_out;

  unsigned short* nodeb = (unsigned short*)d_ws;                      // 25,600,000 B
  unsigned short* w1pp2 = (unsigned short*)((char*)d_ws + 25600000);  // 1,048,576 B

  prep_all_kernel<<<6506, 256, 0, stream>>>(node, W1, nodeb, w1pp2);
  edge_mlp_kernel<<<4096, 512, 0, stream>>>(nodeb, w1pp2, src, dst, b1, W2, b2, out);
}

// Round 15
// 403.875 us; speedup vs baseline: 1.2376x; 1.2376x over previous
//
#include <hip/hip_runtime.h>

#define N_NODES 50000
#define E_EDGES 262144

typedef __attribute__((ext_vector_type(8))) _Float16 f16x8;
typedef __attribute__((ext_vector_type(2))) _Float16 f16x2;
typedef __attribute__((ext_vector_type(16))) float f32x16;

union V16 { uint4 u; f16x8 h; };
union U32 { unsigned u; f16x2 p; };

// pack two f32 -> two f16 (RNE), a in low half
__device__ __forceinline__ unsigned h2pack(float a, float b) {
  union { _Float16 h[2]; unsigned u; } r;
  r.h[0] = (_Float16)a;
  r.h[1] = (_Float16)b;
  return r.u;
}
__device__ __forceinline__ void async_gather16(const void* gptr, void* lptr) {
  __builtin_amdgcn_global_load_lds(
      (const __attribute__((address_space(1))) void*)gptr,
      (__attribute__((address_space(3))) void*)lptr, 16, 0, 0);
}

// ---- fused prep: blocks [0,6250) cvt node fp32->fp16;
//      [6250,6506) repack W1 into 16-B units [step(8)][sq(16)][col(512)],
//      unit = W1[k0..k0+8)[col], k0 = s*256 + step*32 + qd*8. ----
__global__ __launch_bounds__(256) void prep_all_kernel(
    const float* __restrict__ node, const float* __restrict__ w1,
    unsigned short* __restrict__ nodeb, unsigned short* __restrict__ w1pp2) {
  const int bx = blockIdx.x;
  if (bx < 6250) {
    int i = (bx * 256 + threadIdx.x) * 8;
    float4 f0 = *(const float4*)(node + i);
    float4 f1 = *(const float4*)(node + i + 4);
    uint4 o;
    o.x = h2pack(f0.x, f0.y);
    o.y = h2pack(f0.z, f0.w);
    o.z = h2pack(f1.x, f1.y);
    o.w = h2pack(f1.z, f1.w);
    *(uint4*)(nodeb + i) = o;
  } else {
    int t = (bx - 6250) * 256 + threadIdx.x;  // 65536 units
    int step = t >> 13;
    int rem = t & 8191;
    int sq = rem >> 9;
    int col = rem & 511;
    int s = sq >> 2, qd = sq & 3;
    int k0 = s * 256 + step * 32 + qd * 8;
    float f[8];
#pragma unroll
    for (int i = 0; i < 8; ++i) f[i] = w1[(size_t)(k0 + i) * 512 + col];
    uint4 o;
    o.x = h2pack(f[0], f[1]);
    o.y = h2pack(f[2], f[3]);
    o.z = h2pack(f[4], f[5]);
    o.w = h2pack(f[6], f[7]);
    *(uint4*)(w1pp2 + (size_t)t * 8) = o;
  }
}

// ---- main fused kernel: R12 VERBATIM (the session-verified optimum: edge 316 us,
//      total 400 us). 512 thr, 8 waves, 64 edges x 512 cols, wave = 64e x 64c,
//      v_mfma_f32_32x32x16_f16 (32 MFMAs/K-step at the faster 32x32 pipe rate),
//      conflict-free u^(row&31) A-LDS swizzle (bank conflicts = 0), one staging
//      barrier, barrier-free K-loop, LDS cross-wave epilogue reduce, no atomics.
//      CRITICAL INVARIANT (measured R8/R9/R12/R13/R14): arch VGPR 64 + acc AGPR
//      64 = 128 total sits EXACTLY on the waves/SIMD quantization boundary ->
//      4 waves/SIMD (Occ 44%). ANY source perturbation that grows VGPR past 64
//      (fine-grained setprio: 88; coarse setprio: 92; bigger epilogue state)
//      drops to 2 waves/SIMD and costs 25-35%. Do not add scheduler intrinsics,
//      do not enlarge live state, do not add launch_bounds 2nd arg (spills). ----
__global__ __launch_bounds__(512) void edge_mlp_kernel(
    const unsigned short* __restrict__ nodeb,  // [50000][256] fp16
    const unsigned short* __restrict__ w1pp2,  // repacked W1 (see prep)
    const int* __restrict__ src,
    const int* __restrict__ dst,
    const float* __restrict__ b1,
    const float* __restrict__ w2,   // [512][2] fp32
    const float* __restrict__ b2,   // [2] fp32
    float* __restrict__ out) {      // [E][2] fp32 (written once, no pre-init)
  // hi: [0,32K) — 64 edges x 512 B; hj: [32K,64K)
  // 16-B unit slot for (edge row, unit u): row*32 + (u ^ (row&31))
  __shared__ char smem[65536];

  const int tid = threadIdx.x;
  const int wid = tid >> 6;      // 0..7 -> 8 waves x 64 cols = all 512 cols
  const int lane = tid & 63;
  const int l32 = lane & 31;
  const int khalf = lane >> 5;   // k-half within a K16 slice
  const int bx = blockIdx.x;     // 0..4095
  // XCD swizzle: xc = bx&7; neighbor m-tiles share an XCD
  const int xc = bx & 7;
  const int m_idx = (bx >> 3) * 8 + xc;      // 0..4095 (64-edge tiles)
  const int row0 = m_idx * 64;
  const int n0 = wid * 64;

  const char* nodeB = (const char*)nodeb;
  const char* w1B = (const char*)w1pp2;

  // ---- B load: addr = w1s + bQ + s*32768 + slice*16384 + nt2*512 (+step*131072)
  //      (unit index sq = s*4 + slice*2 + khalf; col = n0 + nt2*32 + l32) ----
  const unsigned bQ = (unsigned)(khalf * 8192 + (n0 + l32) * 16);
  const char* w1s = w1B;

  // ---- A reader: row = mt2*32 + l32 (row&31 == l32); unit u = step*4+slice*2+khalf
  //      byte = row*512 + ((u ^ l32) << 4) ----
  const unsigned aXor = (unsigned)l32;
  const unsigned aBase = (unsigned)(l32 * 512);

  f32x16 acc[2][2];
#pragma unroll
  for (int mt2 = 0; mt2 < 2; ++mt2)
#pragma unroll
    for (int nt2 = 0; nt2 < 2; ++nt2)
#pragma unroll
      for (int r = 0; r < 16; ++r)
        acc[mt2][nt2][r] = 0.f;

  // ---- prologue: stage ALL of A (hi+hj, 64 edges x 512 B each region) ----
  // call c stages slots v = c*512+tid; e = v>>5 = c*16 + (tid>>5); w = tid&31.
  // LDS dest linear (base + lane*16); source carries XOR u_src = w ^ (e&31),
  // e&31 = ((c&1)<<4) | (tid>>5).
  {
    const int eh = tid >> 5;                                        // 0..15
#pragma unroll
    for (int c = 0; c < 4; ++c) {
      int e = c * 16 + eh;
      unsigned xv = (unsigned)((((c & 1) << 4) | eh));
      unsigned wsw = (((unsigned)(tid & 31)) ^ xv) << 4;
      unsigned so = ((unsigned)src[row0 + e] << 9) + wsw;
      unsigned do_ = ((unsigned)dst[row0 + e] << 9) + wsw;
      async_gather16(nodeB + so, smem + c * 8192 + wid * 1024);
      async_gather16(nodeB + do_, smem + 32768 + c * 8192 + wid * 1024);
    }
  }
  __syncthreads();  // staging barrier

#pragma unroll 2
  for (int step = 0; step < 8; ++step) {
    // B(t) loads — compiler emits fine-grained vmcnt
    V16 bf[4][2][2];  // [s][slice][nt2]
#pragma unroll
    for (int s = 0; s < 4; ++s)
#pragma unroll
      for (int sl = 0; sl < 2; ++sl)
#pragma unroll
        for (int nt2 = 0; nt2 < 2; ++nt2)
          bf[s][sl][nt2].u = *(const uint4*)(
              w1s + (bQ + (unsigned)(s * 32768 + sl * 16384 + nt2 * 512)));
    // A fragments from LDS (read-only, no sync needed)
    V16 hi[2][2], hj[2][2];  // [mt2][slice]
#pragma unroll
    for (int mt2 = 0; mt2 < 2; ++mt2)
#pragma unroll
      for (int sl = 0; sl < 2; ++sl) {
        unsigned u = (unsigned)(step * 4 + sl * 2 + khalf);
        unsigned ao = (unsigned)(mt2 * 16384) + aBase + ((u ^ aXor) << 4);
        hi[mt2][sl].u = *(const uint4*)(smem + ao);
        hj[mt2][sl].u = *(const uint4*)(smem + 32768 + ao);
      }
    // MFMA s=0 (hi), s=1 (hj)
#pragma unroll
    for (int mt2 = 0; mt2 < 2; ++mt2)
#pragma unroll
      for (int sl = 0; sl < 2; ++sl)
#pragma unroll
        for (int nt2 = 0; nt2 < 2; ++nt2)
          acc[mt2][nt2] = __builtin_amdgcn_mfma_f32_32x32x16_f16(
              hi[mt2][sl].h, bf[0][sl][nt2].h, acc[mt2][nt2], 0, 0, 0);
#pragma unroll
    for (int mt2 = 0; mt2 < 2; ++mt2)
#pragma unroll
      for (int sl = 0; sl < 2; ++sl)
#pragma unroll
        for (int nt2 = 0; nt2 < 2; ++nt2)
          acc[mt2][nt2] = __builtin_amdgcn_mfma_f32_32x32x16_f16(
              hj[mt2][sl].h, bf[1][sl][nt2].h, acc[mt2][nt2], 0, 0, 0);
    // build a2=|hi-hj|, a3=hi*hj with packed fp16 (3 VALU/word), MFMA s=2,3
#pragma unroll
    for (int mt2 = 0; mt2 < 2; ++mt2)
#pragma unroll
      for (int sl = 0; sl < 2; ++sl) {
        const unsigned hw[4] = {hi[mt2][sl].u.x, hi[mt2][sl].u.y, hi[mt2][sl].u.z, hi[mt2][sl].u.w};
        const unsigned jw[4] = {hj[mt2][sl].u.x, hj[mt2][sl].u.y, hj[mt2][sl].u.z, hj[mt2][sl].u.w};
        unsigned d[4], pr[4];
#pragma unroll
        for (int w = 0; w < 4; ++w) {
          U32 hx, jx, dd, pp;
          hx.u = hw[w];
          jx.u = jw[w];
          dd.p = hx.p - jx.p;            // v_pk_add_f16 (neg mod)
          d[w] = dd.u & 0x7fff7fffu;     // abs: clear sign bits (exact)
          pp.p = hx.p * jx.p;            // v_pk_mul_f16
          pr[w] = pp.u;
        }
        V16 a2, a3;
        a2.u = make_uint4(d[0], d[1], d[2], d[3]);
        a3.u = make_uint4(pr[0], pr[1], pr[2], pr[3]);
#pragma unroll
        for (int nt2 = 0; nt2 < 2; ++nt2)
          acc[mt2][nt2] = __builtin_amdgcn_mfma_f32_32x32x16_f16(
              a2.h, bf[2][sl][nt2].h, acc[mt2][nt2], 0, 0, 0);
#pragma unroll
        for (int nt2 = 0; nt2 < 2; ++nt2)
          acc[mt2][nt2] = __builtin_amdgcn_mfma_f32_32x32x16_f16(
              a3.h, bf[3][sl][nt2].h, acc[mt2][nt2], 0, 0, 0);
      }
    w1s += 131072;
  }

  // ---- epilogue: bias + ReLU + W2, 32-lane-half shuffle reduce, LDS cross-wave
  //      reduction (smem reused) + ONE plain store per out element ----
  float* red = (float*)smem;   // [8 waves][64 edges][2] f32 = 4 KB
  __syncthreads();             // all waves done reading A tiles from LDS
  float b1v[2], w20[2], w21[2];
#pragma unroll
  for (int nt2 = 0; nt2 < 2; ++nt2) {
    int gc = n0 + nt2 * 32 + l32;
    b1v[nt2] = b1[gc];
    w20[nt2] = w2[gc * 2 + 0];
    w21[nt2] = w2[gc * 2 + 1];
  }
#pragma unroll
  for (int mt2 = 0; mt2 < 2; ++mt2) {
#pragma unroll
    for (int r = 0; r < 16; ++r) {
      float pc0 = 0.f, pc1 = 0.f;
#pragma unroll
      for (int nt2 = 0; nt2 < 2; ++nt2) {
        float v = fmaxf(acc[mt2][nt2][r] + b1v[nt2], 0.f);
        pc0 = fmaf(v, w20[nt2], pc0);
        pc1 = fmaf(v, w21[nt2], pc1);
      }
      // reduce over the 32-lane half (cols); halves hold different rows
#pragma unroll
      for (int off = 1; off < 32; off <<= 1) {
        pc0 += __shfl_xor(pc0, off);
        pc1 += __shfl_xor(pc1, off);
      }
      // C/D: row = (r&3) + 8*(r>>2) + 4*khalf
      int el = mt2 * 32 + (r & 3) + 8 * (r >> 2) + 4 * khalf;
      if (l32 == 0) red[wid * 128 + el * 2 + 0] = pc0;
      if (l32 == 1) red[wid * 128 + el * 2 + 1] = pc1;
    }
  }
  __syncthreads();
  if (tid < 128) {
    // tid = el*2 + c
    float s = b2[tid & 1];
#pragma unroll
    for (int w = 0; w < 8; ++w) s += red[w * 128 + tid];
    out[(size_t)row0 * 2 + tid] = s;
  }
}

extern "C" void kernel_launch(void* const* d_in, const int* in_sizes, int n_in,
                              void* d_out, int out_size, void* d_ws, size_t ws_size,
                              hipStream_t stream) {
  const float* node = (const float*)d_in[0];
  const int* src = (const int*)d_in[1];
  const int* dst = (const int*)d_in[2];
  const float* W1 = (const float*)d_in[3];
  const float* b1 = (const float*)d_in[4];
  const float* W2 = (const float*)d_in[5];
  const float* b2 = (const float*)d_in[6];
  float* out = (float*)d_out;

  unsigned short* nodeb = (unsigned short*)d_ws;                      // 25,600,000 B
  unsigned short* w1pp2 = (unsigned short*)((char*)d_ws + 25600000);  // 1,048,576 B

  prep_all_kernel<<<6506, 256, 0, stream>>>(node, W1, nodeb, w1pp2);
  edge_mlp_kernel<<<4096, 512, 0, stream>>>(nodeb, w1pp2, src, dst, b1, W2, b2, out);
}